// Round 12
// baseline (223.158 us; speedup 1.0000x reference)
//
#include <hip/hip_runtime.h>
#include <cstdint>

// Problem constants (reference: B,J,D,W,H,EH,L = 128,8192,32,4,128,256,32)
#define BDIM 128
#define JDIM 8192

typedef short s8x __attribute__((ext_vector_type(8)));   // 8 bf16 in 4 VGPRs (MFMA A/B frag)
typedef float f4x __attribute__((ext_vector_type(4)));   // MFMA C/D frag
typedef float f2x __attribute__((ext_vector_type(2)));   // packed-f32 (v_pk_*_f32)

// f32 -> bf16 via scalar casts: compiler fuses pairs into v_cvt_pk_bf16_f32.
__device__ __forceinline__ unsigned short bf16u(float f) {
    return __builtin_bit_cast(unsigned short, (__bf16)f);
}
__device__ __forceinline__ unsigned int pkbf(float lo, float hi) {
    return (unsigned int)bf16u(lo) | ((unsigned int)bf16u(hi) << 16);
}
// unpack a bf16 pair (lo,hi) -> f2x
__device__ __forceinline__ f2x upk(unsigned int w) {
    f2x r;
    r.x = __uint_as_float(w << 16);
    r.y = __uint_as_float(w & 0xffff0000u);
    return r;
}
__device__ __forceinline__ f2x pkfma(f2x a, f2x b, f2x c) {
    return __builtin_elementwise_fma(a, b, c);
}
__device__ __forceinline__ f2x pkmax0(f2x a) {
    f2x z = {0.f, 0.f};
    return __builtin_elementwise_max(a, z);
}

// 16-lane all-reduce sum, each stage ONE v_add_f32 with DPP on src0.
__device__ __forceinline__ float allred16(float x) {
    float t;
    asm("v_add_f32 %0, %1, %1 quad_perm:[1,0,3,2] row_mask:0xf bank_mask:0xf"
        : "=v"(t) : "v"(x));            // lane ^ 1
    asm("v_add_f32 %0, %1, %1 quad_perm:[2,3,0,1] row_mask:0xf bank_mask:0xf"
        : "=v"(x) : "v"(t));            // lane ^ 2
    asm("v_add_f32 %0, %1, %1 row_half_mirror row_mask:0xf bank_mask:0xf"
        : "=v"(t) : "v"(x));            // lane ^ 7
    asm("v_add_f32 %0, %1, %1 row_mirror row_mask:0xf bank_mask:0xf"
        : "=v"(x) : "v"(t));            // lane ^ 15
    return x;
}

// ---------------------------------------------------------------------------
// Kernel 0: 1024 blocks x 8 j: feW[j][h] (bf16) + per-j LN1 moments; block 0
// also writes mean(w0), mean(w0^2) and pre-packed MFMA B-fragments.
// ---------------------------------------------------------------------------
__global__ __launch_bounds__(128) void k_prep(
    const float* __restrict__ fe, const float* __restrict__ hw1,
    const float* __restrict__ hb1,
    const float* __restrict__ hw2, const float* __restrict__ gw1,
    unsigned short* __restrict__ feWb, float* __restrict__ aux,
    float* __restrict__ scal, uint4* __restrict__ fragW)
{
    const int h = threadIdx.x;
    __shared__ float red[2][3];
    const int wv = h >> 6, ln = h & 63;
    float w1r[32];
#pragma unroll
    for (int d = 0; d < 32; ++d) w1r[d] = hw1[(1 + d) * 128 + h];
    const float hb = hb1[h];
    const float w0h = hw1[h];

    for (int q = 0; q < 8; ++q) {
        const int j = blockIdx.x * 8 + q;
        float acc = hb;
#pragma unroll
        for (int d = 0; d < 32; ++d) acc = fmaf(fe[j * 32 + d], w1r[d], acc);
        feWb[(size_t)j * 128 + h] = bf16u(acc);

        float s1 = acc, sx = w0h * acc, s2 = acc * acc;
#pragma unroll
        for (int m = 1; m <= 32; m <<= 1) {
            s1 += __shfl_xor(s1, m); sx += __shfl_xor(sx, m); s2 += __shfl_xor(s2, m);
        }
        if (q) __syncthreads();                 // protect red[] reuse
        if (ln == 0) { red[wv][0] = s1; red[wv][1] = sx; red[wv][2] = s2; }
        __syncthreads();
        if (h == 0) {
            aux[j * 4 + 0] = (red[0][0] + red[1][0]) * (1.f / 128.f);
            aux[j * 4 + 1] = (red[0][1] + red[1][1]) * (1.f / 128.f);
            aux[j * 4 + 2] = (red[0][2] + red[1][2]) * (1.f / 128.f);
        }
    }

    if (blockIdx.x == 0) {
        float a = w0h, b = w0h * w0h;
#pragma unroll
        for (int m = 1; m <= 32; m <<= 1) { a += __shfl_xor(a, m); b += __shfl_xor(b, m); }
        __syncthreads();
        if (ln == 0) { red[wv][0] = a; red[wv][1] = b; }
        __syncthreads();
        if (h == 0) {
            scal[0] = (red[0][0] + red[1][0]) * (1.f / 128.f);
            scal[1] = (red[0][1] + red[1][1]) * (1.f / 128.f);
        }
        // pre-pack per-lane MFMA fragments: [frag][lane], coalesced in k_main.
        if (h < 64) {
            const int cc = h & 15, gg = h >> 4;
#pragma unroll
            for (int nt = 0; nt < 2; ++nt)
#pragma unroll
                for (int t = 0; t < 4; ++t) {
                    const int kb = 32 * t + 8 * gg, n = 16 * nt + cc;
                    uint4 u;
                    u.x = pkbf(hw2[(kb + 0) * 32 + n], hw2[(kb + 1) * 32 + n]);
                    u.y = pkbf(hw2[(kb + 2) * 32 + n], hw2[(kb + 3) * 32 + n]);
                    u.z = pkbf(hw2[(kb + 4) * 32 + n], hw2[(kb + 5) * 32 + n]);
                    u.w = pkbf(hw2[(kb + 6) * 32 + n], hw2[(kb + 7) * 32 + n]);
                    fragW[(nt * 4 + t) * 64 + h] = u;
                }
            uint4 u;
            u.x = pkbf(gw1[(8 * gg + 0) * 16 + cc], gw1[(8 * gg + 1) * 16 + cc]);
            u.y = pkbf(gw1[(8 * gg + 2) * 16 + cc], gw1[(8 * gg + 3) * 16 + cc]);
            u.z = pkbf(gw1[(8 * gg + 4) * 16 + cc], gw1[(8 * gg + 5) * 16 + cc]);
            u.w = pkbf(gw1[(8 * gg + 6) * 16 + cc], gw1[(8 * gg + 7) * 16 + cc]);
            fragW[8 * 64 + h] = u;
        }
    }
}

// ---------------------------------------------------------------------------
// Kernel 1: MFMA rows = 4 cells x 4 j (row = cell*4 + j).  8-wave blocks:
// VGPR=64 (R10) allows 8 waves/SIMD; 4 blocks/CU x 8 waves = 32 waves/CU
// (100% cap) with the same single-round 1024-block grid (R10 was 4x4=16
// waves/CU, Occupancy 31.6%).  Each wave: 4 cells x 32 j (8 batches).
// __launch_bounds__(512,4) caps VGPR at 128 — no spill risk (R3 lesson),
// allocator naturally picks ~64 (same per-wave code as R10).
// ---------------------------------------------------------------------------
__global__ __launch_bounds__(512, 4) void k_main(
    const float* __restrict__ x, const int* __restrict__ mask,
    const unsigned short* __restrict__ feWb, const float* __restrict__ aux,
    const float* __restrict__ scal, const uint4* __restrict__ fragW,
    const float* __restrict__ hw1, const float* __restrict__ ln1w,
    const float* __restrict__ ln1b,
    const float* __restrict__ hb2,
    const float* __restrict__ ln2w, const float* __restrict__ ln2b,
    const float* __restrict__ gb1,
    const float* __restrict__ gw2, const float* __restrict__ gb2,
    float* __restrict__ P, float* __restrict__ SEb)
{
    __shared__ float w0s[128], g1s[128], b1s[128];
    __shared__ float holds[8][576];   // [wave][16 rows x pitch 36] (no parity:
                                      // bounce waits lgkmcnt(0) immediately)
    __shared__ float hsL[512];        // [cell=4][w=4][d=32]
    __shared__ float seL[16];

    const int tid = threadIdx.x, l = tid & 63;
    const int wv = __builtin_amdgcn_readfirstlane(tid >> 6);   // 0..7
    const int c = l & 15, g = l >> 4;
    const int bt = blockIdx.y, bx = blockIdx.x;
    const int b0 = bt * 4;
    const int cell_in = c >> 2, jsub = c & 3;   // input-side row decode

    if (tid < 128) { w0s[tid] = hw1[tid]; g1s[tid] = ln1w[tid]; b1s[tid] = ln1b[tid]; }
    __syncthreads();

    const float mw0 = scal[0], q0 = scal[1];

    // pre-packed B-fragments: 9 coalesced dwordx4 loads
    s8x wf[2][4];
#pragma unroll
    for (int nt = 0; nt < 2; ++nt)
#pragma unroll
        for (int t = 0; t < 4; ++t)
            wf[nt][t] = __builtin_bit_cast(s8x, fragW[(nt * 4 + t) * 64 + l]);
    const s8x g1f = __builtin_bit_cast(s8x, fragW[8 * 64 + l]);

    const float hb2a = hb2[c],      hb2b = hb2[16 + c];
    const float g2a  = ln2w[c],     g2b  = ln2w[16 + c];
    const float z2a  = ln2b[c],     z2b  = ln2b[16 + c];
    const float gb1c = gb1[c];
    const float L2E  = 1.442695040888963f;
    float gw2c[4], gb2l[4];
#pragma unroll
    for (int w = 0; w < 4; ++w) {
        gw2c[w] = gw2[c * 4 + w];
        gb2l[w] = fmaf(gb2[w], L2E, -10.f * L2E);   // fold (+gb2, -10)*log2e
    }

    const int j0 = (bx * 8 + wv) * 32;   // 8 waves x 32 j cover 256 j per block
    const float* xrow = x + (size_t)(b0 + cell_in) * JDIM;
    const int*   mrow = mask + (size_t)(b0 + cell_in) * JDIM;

    f2x   hsacc[4];    // [w] = {sum d=c, d=16+c} for cell=g
    float seacc[4];
#pragma unroll
    for (int w = 0; w < 4; ++w) { hsacc[w].x = 0.f; hsacc[w].y = 0.f; seacc[w] = 0.f; }

    for (int bi = 0; bi < 8; ++bi) {
        const int jb = j0 + bi * 4;
        const int j  = jb + jsub;

        // ---- phase A: per-lane LN1 scalars for row c's j ----
        const float xv = xrow[j];
        const int   mv = mrow[j];
        const float4 au = *(const float4*)(aux + (size_t)j * 4);
        const float mu = fmaf(xv, mw0, au.x);
        const float e2 = fmaf(xv * xv, q0, fmaf(2.f * xv, au.y, au.z));
        const float rs = rsqrtf(e2 - mu * mu + 1e-5f);
        const float nms = -mu * rs;
        const f2x xv2 = {xv, xv}, rs2 = {rs, rs}, nm2 = {nms, nms};

        // ---- phase B: h-compute for row c + h_w2 MFMAs (covers 4 j) ----
        f4x ca = {0.f, 0.f, 0.f, 0.f}, cb = {0.f, 0.f, 0.f, 0.f};
        const unsigned short* fj = feWb + (size_t)j * 128;
#pragma unroll
        for (int t = 0; t < 4; ++t) {
            const int kb = 32 * t + 8 * g;
            const uint4 fw = *(const uint4*)(fj + kb);
            const unsigned int fwv[4] = {fw.x, fw.y, fw.z, fw.w};
            const f2x* wp = (const f2x*)&w0s[kb];
            const f2x* gp = (const f2x*)&g1s[kb];
            const f2x* bp = (const f2x*)&b1s[kb];
            unsigned int res[4];
#pragma unroll
            for (int q = 0; q < 4; ++q) {
                f2x h2 = pkfma(xv2, wp[q], upk(fwv[q]));   // pre = xv*w0 + feW
                h2 = pkfma(h2, rs2, nm2);                  // (pre-mu)*rs
                h2 = pkfma(h2, gp[q], bp[q]);              // *g1 + b1
                h2 = pkmax0(h2);                           // relu
                res[q] = pkbf(h2.x, h2.y);
            }
            const uint4 u = make_uint4(res[0], res[1], res[2], res[3]);
            const s8x af = __builtin_bit_cast(s8x, u);
            ca = __builtin_amdgcn_mfma_f32_16x16x32_bf16(af, wf[0][t], ca, 0, 0, 0);
            cb = __builtin_amdgcn_mfma_f32_16x16x32_bf16(af, wf[1][t], cb, 0, 0, 0);
        }

        // ---- phase C: +b2, LN2 (DPP reduce over D), relu. rows 4g+r ----
        float v0[4], v1[4], sr[4], qr[4];
#pragma unroll
        for (int r = 0; r < 4; ++r) {
            v0[r] = ca[r] + hb2a;
            v1[r] = cb[r] + hb2b;
            sr[r] = v0[r] + v1[r];
            qr[r] = v0[r] * v0[r] + v1[r] * v1[r];
        }
#pragma unroll
        for (int r = 0; r < 4; ++r) { sr[r] = allred16(sr[r]); qr[r] = allred16(qr[r]); }
        float ho0[4], ho1[4];
#pragma unroll
        for (int r = 0; r < 4; ++r) {
            const float m2   = sr[r] * 0.03125f;
            const float rs2b = rsqrtf(fmaf(qr[r], 0.03125f, -m2 * m2) + 1e-5f);
            const float nm2b = -m2 * rs2b;
            ho0[r] = fmaxf(fmaf(fmaf(v0[r], rs2b, nm2b), g2a, z2a), 0.f);
            ho1[r] = fmaxf(fmaf(fmaf(v1[r], rs2b, nm2b), g2b, z2b), 0.f);
        }

        // ---- phase D: LDS transpose bounce + gate MFMA (covers 4 j) ----
        float* hp = &holds[wv][0];
#pragma unroll
        for (int r = 0; r < 4; ++r) {
            hp[(4 * g + r) * 36 + c]      = ho0[r];
            hp[(4 * g + r) * 36 + 16 + c] = ho1[r];
        }
        asm volatile("s_waitcnt lgkmcnt(0)" ::: "memory");
        const float4 ra  = *(const float4*)&hp[c * 36 + 8 * g];
        const float4 rb2 = *(const float4*)&hp[c * 36 + 8 * g + 4];
        uint4 ua;
        ua.x = pkbf(ra.x, ra.y);   ua.y = pkbf(ra.z, ra.w);
        ua.z = pkbf(rb2.x, rb2.y); ua.w = pkbf(rb2.z, rb2.w);
        const s8x af2 = __builtin_bit_cast(s8x, ua);
        f4x zz = {0.f, 0.f, 0.f, 0.f};
        const f4x gc = __builtin_amdgcn_mfma_f32_16x16x32_bf16(af2, g1f, zz, 0, 0, 0);

        // ---- phase E: gate2 reduce + exp + weighted accum (covers 4 j) ----
        float pw[16];
#pragma unroll
        for (int r = 0; r < 4; ++r) {
            const float g1r = fmaxf(gc[r] + gb1c, 0.f);
#pragma unroll
            for (int w = 0; w < 4; ++w) pw[r * 4 + w] = g1r * gw2c[w];
        }
#pragma unroll
        for (int i = 0; i < 16; ++i) pw[i] = allred16(pw[i]);

        const unsigned long long bm = __ballot(mv > 0);
#pragma unroll
        for (int r = 0; r < 4; ++r) {
            const float fm = (float)((bm >> (4 * g + r)) & 1ull);
            const f2x ho2 = {ho0[r], ho1[r]};
#pragma unroll
            for (int w = 0; w < 4; ++w) {
                float t2 = fmaf(pw[r * 4 + w], L2E, gb2l[w]);
                t2 = __builtin_amdgcn_fmed3f(t2, -20.f * L2E, 0.f);
                const float e = fm * __builtin_amdgcn_exp2f(t2);
                seacc[w] += e;
                const f2x e2v = {e, e};
                hsacc[w] = pkfma(e2v, ho2, hsacc[w]);
            }
        }
    }

    // combine the 8 waves' partials in LDS (barrier ladder)
    for (int ww = 0; ww < 8; ++ww) {
        __syncthreads();
        if (wv == ww) {
#pragma unroll
            for (int w = 0; w < 4; ++w)
#pragma unroll
                for (int nt = 0; nt < 2; ++nt) {
                    const int idx = (g * 4 + w) * 32 + 16 * nt + c;   // [cell][w][d]
                    const float val = nt ? hsacc[w].y : hsacc[w].x;
                    if (ww == 0) hsL[idx] = val;
                    else         hsL[idx] += val;
                }
            if (c == 0) {
#pragma unroll
                for (int w = 0; w < 4; ++w) {
                    const int si = g * 4 + w;
                    if (ww == 0) seL[si] = seacc[w];
                    else         seL[si] += seacc[w];
                }
            }
        }
    }
    __syncthreads();
    const size_t base = ((size_t)bt * 32 + bx) * 512;
    if (tid < 512) P[base + tid] = hsL[tid];
    if (tid < 16) SEb[((size_t)bt * 32 + bx) * 16 + tid] = seL[tid];
}

// ---------------------------------------------------------------------------
// Kernel 2: per b: reduce the 32 j-block partials, head_sums = hs/sumexp,
// comb-LN-relu, two e-layers with LN + relu, split mu / logvar.
// ---------------------------------------------------------------------------
__global__ __launch_bounds__(128) void k_tail(
    const float* __restrict__ P, const float* __restrict__ SEb,
    const float* __restrict__ cw, const float* __restrict__ cbv,
    const float* __restrict__ clnw, const float* __restrict__ clnb,
    const float* __restrict__ ew1, const float* __restrict__ eb1,
    const float* __restrict__ l1w, const float* __restrict__ l1b,
    const float* __restrict__ ew2, const float* __restrict__ eb2,
    const float* __restrict__ l2w, const float* __restrict__ l2b,
    float* __restrict__ out)
{
    const int b = blockIdx.x, t = threadIdx.x;
    const int bt = b >> 2, cell = b & 3;
    __shared__ float hsLs[128], combL[32], hL[256], seW[4], red[4];

    // hs partial: t -> (w = t>>5, d = t&31)
    const float* Pb = P + (size_t)bt * 32 * 512 + (size_t)(cell * 4 + (t >> 5)) * 32 + (t & 31);
    float sacc = 0.f;
#pragma unroll 4
    for (int q = 0; q < 32; ++q) sacc += Pb[(size_t)q * 512];

    if (t < 4) {
        float s = 0.f;
        for (int q = 0; q < 32; ++q) s += SEb[((size_t)bt * 32 + q) * 16 + cell * 4 + t];
        seW[t] = s;
    }
    __syncthreads();
    const bool has = seW[0] > 0.f;
    hsLs[t] = has ? sacc / seW[t >> 5] : 0.f;
    __syncthreads();

    if (t < 32) {
        float cv = cbv[t];
#pragma unroll 4
        for (int f = 0; f < 128; ++f) cv = fmaf(hsLs[f], cw[f * 32 + t], cv);
        float s = cv, q = cv * cv;
#pragma unroll
        for (int m = 1; m <= 16; m <<= 1) { s += __shfl_xor(s, m); q += __shfl_xor(q, m); }
        const float mu = s * (1.f / 32.f);
        const float rsg = rsqrtf(fmaf(q, 1.f / 32.f, -mu * mu) + 1e-5f);
        const float v = fmaf(fmaf(cv, rsg, -mu * rsg), clnw[t], clnb[t]);
        combL[t] = has ? fmaxf(v, 0.f) : 0.f;
    }
    __syncthreads();

    float h0 = eb1[t], h1v = eb1[t + 128];
#pragma unroll 4
    for (int d = 0; d < 32; ++d) {
        const float cd = combL[d];
        h0  = fmaf(cd, ew1[d * 256 + t], h0);
        h1v = fmaf(cd, ew1[d * 256 + t + 128], h1v);
    }
    {
        float s = h0 + h1v, q = h0 * h0 + h1v * h1v;
#pragma unroll
        for (int m = 1; m <= 32; m <<= 1) { s += __shfl_xor(s, m); q += __shfl_xor(q, m); }
        const int wv = t >> 6, ln = t & 63;
        if (ln == 0) { red[wv * 2] = s; red[wv * 2 + 1] = q; }
    }
    __syncthreads();
    {
        const float S = red[0] + red[2], Q = red[1] + red[3];
        const float mu1 = S * (1.f / 256.f);
        const float rs1 = rsqrtf(fmaf(Q, 1.f / 256.f, -mu1 * mu1) + 1e-5f);
        hL[t]       = fmaxf(fmaf(fmaf(h0,  rs1, -mu1 * rs1), l1w[t],       l1b[t]),       0.f);
        hL[t + 128] = fmaxf(fmaf(fmaf(h1v, rs1, -mu1 * rs1), l1w[t + 128], l1b[t + 128]), 0.f);
    }
    __syncthreads();

    if (t < 64) {
        float ov = eb2[t];
#pragma unroll 4
        for (int m = 0; m < 256; ++m) ov = fmaf(hL[m], ew2[m * 64 + t], ov);
        float s = ov, q = ov * ov;
#pragma unroll
        for (int m = 1; m <= 32; m <<= 1) { s += __shfl_xor(s, m); q += __shfl_xor(q, m); }
        const float mu2 = s * (1.f / 64.f);
        const float rs2 = rsqrtf(fmaf(q, 1.f / 64.f, -mu2 * mu2) + 1e-5f);
        const float o = fmaxf(fmaf(fmaf(ov, rs2, -mu2 * rs2), l2w[t], l2b[t]), 0.f);
        if (t < 32) out[b * 32 + t] = o;
        else        out[4096 + b * 32 + (t - 32)] = o;
    }
}

// ---------------------------------------------------------------------------
extern "C" void kernel_launch(void* const* d_in, const int* in_sizes, int n_in,
                              void* d_out, int out_size, void* d_ws, size_t ws_size,
                              hipStream_t stream)
{
    (void)in_sizes; (void)n_in; (void)out_size; (void)ws_size;
    const float* x    = (const float*)d_in[0];
    const int*   mask = (const int*)d_in[1];
    const float* fe   = (const float*)d_in[2];
    const float* hw1  = (const float*)d_in[3];
    const float* hb1  = (const float*)d_in[4];
    const float* ln1w = (const float*)d_in[5];
    const float* ln1b = (const float*)d_in[6];
    const float* hw2  = (const float*)d_in[7];
    const float* hb2  = (const float*)d_in[8];
    const float* ln2w = (const float*)d_in[9];
    const float* ln2b = (const float*)d_in[10];
    const float* gw1  = (const float*)d_in[11];
    const float* gb1  = (const float*)d_in[12];
    const float* gw2  = (const float*)d_in[13];
    const float* gb2  = (const float*)d_in[14];
    const float* cw   = (const float*)d_in[15];
    const float* cbv  = (const float*)d_in[16];
    const float* clnw = (const float*)d_in[17];
    const float* clnb = (const float*)d_in[18];
    const float* ew1  = (const float*)d_in[19];
    const float* eb1  = (const float*)d_in[20];
    const float* l1w  = (const float*)d_in[21];
    const float* l1b  = (const float*)d_in[22];
    const float* ew2  = (const float*)d_in[23];
    const float* eb2  = (const float*)d_in[24];
    const float* l2w  = (const float*)d_in[25];
    const float* l2b  = (const float*)d_in[26];

    const size_t fragOff = (2u << 20) + (128u << 10) + 256u;          // feWb + aux + scal
    const size_t pOff    = fragOff + 9u * 64u * 16u;                  // + 9KB fragments
    const size_t seOff   = pOff + (size_t)32 * 32 * 512 * 4;          // + 2MB P

    char* ws = (char*)d_ws;
    unsigned short* feWb = (unsigned short*)ws;                       // 2 MB
    float* aux   = (float*)(ws + (2u << 20));                         // 128 KB
    float* scal  = (float*)(ws + (2u << 20) + (128u << 10));          // 256 B
    uint4* fragW = (uint4*)(ws + fragOff);                            // 9 KB
    float* P     = (float*)(ws + pOff);                               // 2 MB
    float* SEb   = (float*)(ws + seOff);                              // 64 KB

    hipLaunchKernelGGL(k_prep, dim3(JDIM / 8), dim3(128), 0, stream,
                       fe, hw1, hb1, hw2, gw1, feWb, aux, scal, fragW);
    hipLaunchKernelGGL(k_main, dim3(32, 32), dim3(512), 0, stream,
                       x, mask, feWb, aux, scal, fragW,
                       hw1, ln1w, ln1b, hb2, ln2w, ln2b,
                       gb1, gw2, gb2, P, SEb);
    hipLaunchKernelGGL(k_tail, dim3(BDIM), dim3(128), 0, stream,
                       P, SEb, cw, cbv, clnw, clnb,
                       ew1, eb1, l1w, l1b, ew2, eb2, l2w, l2b,
                       (float*)d_out);
}